// Round 1
// baseline (2494.722 us; speedup 1.0000x reference)
//
#include <hip/hip_runtime.h>
#include <math.h>

#define B_ 4
#define L_ 2048
#define DM 1024
#define H_ 16
#define HD_ 64
#define NH_ 64            // B_*H_
#define EPS_ 1e-6f

__device__ __forceinline__ float sigmoidf_(float x) { return 1.0f / (1.0f + expf(-x)); }

// ---------------------------------------------------------------------------
// GEMM: C = A @ W^T + bias.  A [M,DM] row-major, W [DM,DM] row-major (NT form).
// QKV variant: blockIdx.z selects (Wq,bq)->q / (Wk,bk)->k / (Wv,bv)->v.
// Q,K get sigmoid. Store in [B,H,L,HD] layout.
// ---------------------------------------------------------------------------
__global__ __launch_bounds__(256) void gemm_qkv_kernel(
    const float* __restrict__ x,
    const float* __restrict__ Wq, const float* __restrict__ bq,
    const float* __restrict__ Wk, const float* __restrict__ bk,
    const float* __restrict__ Wv, const float* __restrict__ bv,
    float* __restrict__ qb, float* __restrict__ kb, float* __restrict__ vb)
{
    const int z = blockIdx.z;
    const float* __restrict__ W    = (z == 0) ? Wq : (z == 1) ? Wk : Wv;
    const float* __restrict__ bias = (z == 0) ? bq : (z == 1) ? bk : bv;
    float* __restrict__ outp       = (z == 0) ? qb : (z == 1) ? kb : vb;

    __shared__ float As[16][64];
    __shared__ float Bs[16][64];
    const int row0 = blockIdx.y * 64;
    const int col0 = blockIdx.x * 64;
    const int tid = threadIdx.x;
    const int tx = tid & 15;
    const int ty = tid >> 4;
    float acc[4][4] = {{0.f}};

    for (int k0 = 0; k0 < DM; k0 += 16) {
        for (int i = tid; i < 1024; i += 256) {
            const int r  = i >> 4;
            const int kk = i & 15;
            As[kk][r] = x[(size_t)(row0 + r) * DM + (k0 + kk)];
            Bs[kk][r] = W[(size_t)(col0 + r) * DM + (k0 + kk)];
        }
        __syncthreads();
        #pragma unroll
        for (int kk = 0; kk < 16; ++kk) {
            float a0 = As[kk][ty * 4 + 0];
            float a1 = As[kk][ty * 4 + 1];
            float a2 = As[kk][ty * 4 + 2];
            float a3 = As[kk][ty * 4 + 3];
            float b0 = Bs[kk][tx * 4 + 0];
            float b1 = Bs[kk][tx * 4 + 1];
            float b2 = Bs[kk][tx * 4 + 2];
            float b3 = Bs[kk][tx * 4 + 3];
            acc[0][0] += a0 * b0; acc[0][1] += a0 * b1; acc[0][2] += a0 * b2; acc[0][3] += a0 * b3;
            acc[1][0] += a1 * b0; acc[1][1] += a1 * b1; acc[1][2] += a1 * b2; acc[1][3] += a1 * b3;
            acc[2][0] += a2 * b0; acc[2][1] += a2 * b1; acc[2][2] += a2 * b2; acc[2][3] += a2 * b3;
            acc[3][0] += a3 * b0; acc[3][1] += a3 * b1; acc[3][2] += a3 * b2; acc[3][3] += a3 * b3;
        }
        __syncthreads();
    }

    #pragma unroll
    for (int i2 = 0; i2 < 4; ++i2) {
        const int i = row0 + ty * 4 + i2;   // global row in [0, B*L)
        const int n = i >> 11;              // / L_
        const int l = i & (L_ - 1);
        #pragma unroll
        for (int j2 = 0; j2 < 4; ++j2) {
            const int j = col0 + tx * 4 + j2;   // global col in [0, DM)
            float v = acc[i2][j2] + bias[j];
            if (z < 2) v = sigmoidf_(v);
            const int h  = j >> 6;
            const int dd = j & 63;
            outp[(((size_t)(n * H_ + h)) * L_ + l) * HD_ + dd] = v;
        }
    }
}

// Final GEMM: out = attn @ Wo^T + bo, plain [B*L, DM] store.
__global__ __launch_bounds__(256) void gemm_out_kernel(
    const float* __restrict__ A,
    const float* __restrict__ W, const float* __restrict__ bias,
    float* __restrict__ outp)
{
    __shared__ float As[16][64];
    __shared__ float Bs[16][64];
    const int row0 = blockIdx.y * 64;
    const int col0 = blockIdx.x * 64;
    const int tid = threadIdx.x;
    const int tx = tid & 15;
    const int ty = tid >> 4;
    float acc[4][4] = {{0.f}};

    for (int k0 = 0; k0 < DM; k0 += 16) {
        for (int i = tid; i < 1024; i += 256) {
            const int r  = i >> 4;
            const int kk = i & 15;
            As[kk][r] = A[(size_t)(row0 + r) * DM + (k0 + kk)];
            Bs[kk][r] = W[(size_t)(col0 + r) * DM + (k0 + kk)];
        }
        __syncthreads();
        #pragma unroll
        for (int kk = 0; kk < 16; ++kk) {
            float a0 = As[kk][ty * 4 + 0];
            float a1 = As[kk][ty * 4 + 1];
            float a2 = As[kk][ty * 4 + 2];
            float a3 = As[kk][ty * 4 + 3];
            float b0 = Bs[kk][tx * 4 + 0];
            float b1 = Bs[kk][tx * 4 + 1];
            float b2 = Bs[kk][tx * 4 + 2];
            float b3 = Bs[kk][tx * 4 + 3];
            acc[0][0] += a0 * b0; acc[0][1] += a0 * b1; acc[0][2] += a0 * b2; acc[0][3] += a0 * b3;
            acc[1][0] += a1 * b0; acc[1][1] += a1 * b1; acc[1][2] += a1 * b2; acc[1][3] += a1 * b3;
            acc[2][0] += a2 * b0; acc[2][1] += a2 * b1; acc[2][2] += a2 * b2; acc[2][3] += a2 * b3;
            acc[3][0] += a3 * b0; acc[3][1] += a3 * b1; acc[3][2] += a3 * b2; acc[3][3] += a3 * b3;
        }
        __syncthreads();
    }

    #pragma unroll
    for (int i2 = 0; i2 < 4; ++i2) {
        const int i = row0 + ty * 4 + i2;
        #pragma unroll
        for (int j2 = 0; j2 < 4; ++j2) {
            const int j = col0 + tx * 4 + j2;
            outp[(size_t)i * DM + j] = acc[i2][j2] + bias[j];
        }
    }
}

// ---------------------------------------------------------------------------
// Column sums over L per (n,h): qsum[nh][d] = sum_l q[nh][l][d], same for k.
// ---------------------------------------------------------------------------
__global__ __launch_bounds__(256) void colsum_kernel(
    const float* __restrict__ q, const float* __restrict__ k,
    float* __restrict__ qsum, float* __restrict__ ksum)
{
    const int nh = blockIdx.x;
    const float* qp = q + (size_t)nh * L_ * HD_;
    const float* kp = k + (size_t)nh * L_ * HD_;
    const int d = threadIdx.x & 63;
    const int c = threadIdx.x >> 6;   // 0..3
    float qs = 0.f, ks = 0.f;
    for (int l = c; l < L_; l += 4) {
        qs += qp[(size_t)l * HD_ + d];
        ks += kp[(size_t)l * HD_ + d];
    }
    __shared__ float sq[4][64];
    __shared__ float sk[4][64];
    sq[c][d] = qs; sk[c][d] = ks;
    __syncthreads();
    if (c == 0) {
        qsum[nh * 64 + d] = sq[0][d] + sq[1][d] + sq[2][d] + sq[3][d];
        ksum[nh * 64 + d] = sk[0][d] + sk[1][d] + sk[2][d] + sk[3][d];
    }
}

// ---------------------------------------------------------------------------
// Stage 1: per (n,h,l) compute sink_incoming (si) and source_outgoing (so),
// and accumulate qsi[d]=sum_l q*si, kso[d]=sum_l k*so.
// ---------------------------------------------------------------------------
__global__ __launch_bounds__(256) void stage1_kernel(
    const float* __restrict__ q, const float* __restrict__ k,
    const float* __restrict__ qsum, const float* __restrict__ ksum,
    float* __restrict__ si, float* __restrict__ so,
    float* __restrict__ qsi, float* __restrict__ kso)
{
    const int nh = blockIdx.x;
    const float* qp = q + (size_t)nh * L_ * HD_;
    const float* kp = k + (size_t)nh * L_ * HD_;
    const int lane = threadIdx.x & 63;
    const int w = threadIdx.x >> 6;   // wave 0..3
    const float ksv = ksum[nh * 64 + lane] + EPS_;
    const float qsv = qsum[nh * 64 + lane] + EPS_;
    float qsi_acc = 0.f, kso_acc = 0.f;
    for (int l = w; l < L_; l += 4) {
        const float qv = qp[(size_t)l * HD_ + lane];
        const float kv = kp[(size_t)l * HD_ + lane];
        float a = (qv + EPS_) * ksv;
        float b = (kv + EPS_) * qsv;
        #pragma unroll
        for (int off = 32; off >= 1; off >>= 1) {
            a += __shfl_xor(a, off, 64);
            b += __shfl_xor(b, off, 64);
        }
        const float siv = 1.f / a;
        const float sov = 1.f / b;
        if (lane == 0) { si[nh * L_ + l] = siv; so[nh * L_ + l] = sov; }
        qsi_acc += qv * siv;
        kso_acc += kv * sov;
    }
    __shared__ float s1[4][64];
    __shared__ float s2[4][64];
    s1[w][lane] = qsi_acc; s2[w][lane] = kso_acc;
    __syncthreads();
    if (w == 0) {
        qsi[nh * 64 + lane] = s1[0][lane] + s1[1][lane] + s1[2][lane] + s1[3][lane];
        kso[nh * 64 + lane] = s2[0][lane] + s2[1][lane] + s2[2][lane] + s2[3][lane];
    }
}

// ---------------------------------------------------------------------------
// Stage 2: per (n,h,l): conserved_sink -> sink_allocation (sa = sigmoid),
// conserved_source (clipped) -> softmax over l, scaled by S  (sc).
// ---------------------------------------------------------------------------
__global__ __launch_bounds__(256) void stage2_kernel(
    const float* __restrict__ q, const float* __restrict__ k,
    const float* __restrict__ qsi, const float* __restrict__ kso,
    float* __restrict__ sa, float* __restrict__ sc)
{
    const int nh = blockIdx.x;
    const float* qp = q + (size_t)nh * L_ * HD_;
    const float* kp = k + (size_t)nh * L_ * HD_;
    const int lane = threadIdx.x & 63;
    const int w = threadIdx.x >> 6;
    const float ksov = kso[nh * 64 + lane] + EPS_;
    const float qsiv = qsi[nh * 64 + lane] + EPS_;
    float psum = 0.f;
    for (int l = w; l < L_; l += 4) {
        float a = (qp[(size_t)l * HD_ + lane] + EPS_) * ksov;  // conserved_sink
        float b = (kp[(size_t)l * HD_ + lane] + EPS_) * qsiv;  // conserved_source
        #pragma unroll
        for (int off = 32; off >= 1; off >>= 1) {
            a += __shfl_xor(a, off, 64);
            b += __shfl_xor(b, off, 64);
        }
        b = fminf(1.f, fmaxf(-1.f, b));
        const float p = expf(b);    // softmax numerator; b in [-1,1] so safe
        if (lane == 0) {
            sa[nh * L_ + l] = sigmoidf_(a);   // * (L/S) == 1
            sc[nh * L_ + l] = p;
        }
        psum += p;   // same value on all lanes; use wave w's copy below
    }
    __shared__ float sp[4];
    if (lane == 0) sp[w] = psum;
    __syncthreads();
    const float tot = sp[0] + sp[1] + sp[2] + sp[3];
    const float scale = (float)L_ / tot;   // softmax * S, S == L
    for (int i = threadIdx.x; i < L_; i += 256) sc[nh * L_ + i] *= scale;
}

// ---------------------------------------------------------------------------
// kv[nh][d][m] = sum_l k[nh][l][d] * v[nh][l][m] * sc[nh][l]
// One block per nh; thread owns m = tid&63, d-block (tid>>6)*16.
// ---------------------------------------------------------------------------
__global__ __launch_bounds__(256) void kv_kernel(
    const float* __restrict__ k, const float* __restrict__ v,
    const float* __restrict__ sc, float* __restrict__ kvb)
{
    const int nh = blockIdx.x;
    const float* kp = k + (size_t)nh * L_ * HD_;
    const float* vp = v + (size_t)nh * L_ * HD_;
    const float* scp = sc + (size_t)nh * L_;
    const int m  = threadIdx.x & 63;
    const int dg = threadIdx.x >> 6;   // 0..3
    float acc[16] = {0.f};
    __shared__ float ks[32][64];
    __shared__ float vs[32][64];
    for (int l0 = 0; l0 < L_; l0 += 32) {
        for (int i = threadIdx.x; i < 32 * 64; i += 256) {
            const int ll = i >> 6;
            const int dd = i & 63;
            ks[ll][dd] = kp[(size_t)(l0 + ll) * HD_ + dd];
            vs[ll][dd] = vp[(size_t)(l0 + ll) * HD_ + dd] * scp[l0 + ll];
        }
        __syncthreads();
        #pragma unroll 8
        for (int ll = 0; ll < 32; ++ll) {
            const float vv = vs[ll][m];
            #pragma unroll
            for (int dd = 0; dd < 16; ++dd) acc[dd] += ks[ll][dg * 16 + dd] * vv;
        }
        __syncthreads();
    }
    #pragma unroll
    for (int dd = 0; dd < 16; ++dd)
        kvb[(size_t)nh * 4096 + (dg * 16 + dd) * 64 + m] = acc[dd];
}

// ---------------------------------------------------------------------------
// attn[n][l][h*64+m] = sa[l] * si[l] * sum_d q[nh][l][d] * kv[nh][d][m]
// Block: (nh, l-tile of 64).
// ---------------------------------------------------------------------------
__global__ __launch_bounds__(256) void out_kernel(
    const float* __restrict__ q, const float* __restrict__ kvb,
    const float* __restrict__ si, const float* __restrict__ sa,
    float* __restrict__ attn)
{
    const int nh = blockIdx.x;
    const int n = nh >> 4;    // / H_
    const int h = nh & 15;
    const int l0 = blockIdx.y * 64;
    __shared__ float kvs[64][64];
    __shared__ float qs[64][64];
    for (int i = threadIdx.x; i < 4096; i += 256)
        kvs[i >> 6][i & 63] = kvb[(size_t)nh * 4096 + i];
    for (int i = threadIdx.x; i < 4096; i += 256) {
        const int ll = i >> 6;
        const int dd = i & 63;
        qs[ll][dd] = q[((size_t)nh * L_ + (l0 + ll)) * HD_ + dd];
    }
    __syncthreads();
    const int m = threadIdx.x & 63;
    const int lg = threadIdx.x >> 6;
    for (int ll = lg; ll < 64; ll += 4) {
        const int l = l0 + ll;
        float acc = 0.f;
        #pragma unroll
        for (int d = 0; d < 64; ++d) acc += qs[ll][d] * kvs[d][m];
        const float val = acc * si[nh * L_ + l] * sa[nh * L_ + l];
        attn[((size_t)n * L_ + l) * DM + h * 64 + m] = val;
    }
}

extern "C" void kernel_launch(void* const* d_in, const int* in_sizes, int n_in,
                              void* d_out, int out_size, void* d_ws, size_t ws_size,
                              hipStream_t stream)
{
    const float* x  = (const float*)d_in[0];
    const float* Wq = (const float*)d_in[1];
    const float* bq = (const float*)d_in[2];
    const float* Wk = (const float*)d_in[3];
    const float* bk = (const float*)d_in[4];
    const float* Wv = (const float*)d_in[5];
    const float* bv = (const float*)d_in[6];
    const float* Wo = (const float*)d_in[7];
    const float* bo = (const float*)d_in[8];
    float* out = (float*)d_out;

    float* ws = (float*)d_ws;
    size_t off = 0;
    const size_t big = (size_t)B_ * L_ * DM;   // 8,388,608
    float* qbuf = ws + off; off += big;
    float* kbuf = ws + off; off += big;
    float* vbuf = ws + off; off += big;
    float* attn = ws + off; off += big;
    float* qsum = ws + off; off += NH_ * 64;
    float* ksum = ws + off; off += NH_ * 64;
    float* qsi  = ws + off; off += NH_ * 64;
    float* kso  = ws + off; off += NH_ * 64;
    float* si   = ws + off; off += NH_ * L_;
    float* so   = ws + off; off += NH_ * L_;
    float* sa   = ws + off; off += NH_ * L_;
    float* sc   = ws + off; off += NH_ * L_;
    float* kvb  = ws + off; off += (size_t)NH_ * 64 * 64;

    dim3 gqkv(DM / 64, (B_ * L_) / 64, 3);
    gemm_qkv_kernel<<<gqkv, 256, 0, stream>>>(x, Wq, bq, Wk, bk, Wv, bv, qbuf, kbuf, vbuf);

    colsum_kernel<<<NH_, 256, 0, stream>>>(qbuf, kbuf, qsum, ksum);
    stage1_kernel<<<NH_, 256, 0, stream>>>(qbuf, kbuf, qsum, ksum, si, so, qsi, kso);
    stage2_kernel<<<NH_, 256, 0, stream>>>(qbuf, kbuf, qsi, kso, sa, sc);
    kv_kernel<<<NH_, 256, 0, stream>>>(kbuf, vbuf, sc, kvb);
    out_kernel<<<dim3(NH_, L_ / 64), 256, 0, stream>>>(qbuf, kvb, si, sa, attn);

    dim3 gout(DM / 64, (B_ * L_) / 64);
    gemm_out_kernel<<<gout, 256, 0, stream>>>(attn, Wo, bo, out);
}

// Round 2
// 416.756 us; speedup vs baseline: 5.9860x; 5.9860x over previous
//
#include <hip/hip_runtime.h>
#include <math.h>

#define B_ 4
#define L_ 2048
#define DM 1024
#define H_ 16
#define HD_ 64
#define NH_ 64            // B_*H_
#define EPS_ 1e-6f

typedef float f32x4 __attribute__((ext_vector_type(4)));
typedef short short8 __attribute__((ext_vector_type(8)));

typedef __attribute__((address_space(3))) void lds_v;
typedef const __attribute__((address_space(1))) void glb_v;
#define GLOAD16(g, l) __builtin_amdgcn_global_load_lds((glb_v*)(g), (lds_v*)(l), 16, 0, 0)

__device__ __forceinline__ float sigmoidf_(float x) { return 1.0f / (1.0f + expf(-x)); }

// round-to-nearest-even f32 -> bf16 bits
__device__ __forceinline__ short f2bf(float x) {
    unsigned u = __float_as_uint(x);
    unsigned r = (u + 0x7FFFu + ((u >> 16) & 1u)) >> 16;
    return (short)r;
}
__device__ __forceinline__ float bf2f(short h) {
    return __uint_as_float(((unsigned)(unsigned short)h) << 16);
}

// ---------------------------------------------------------------------------
// Split f32 array into bf16 hi/lo (x = hi + lo to ~2^-17 relative).
// ---------------------------------------------------------------------------
__global__ __launch_bounds__(256) void split_kernel(
    const float* __restrict__ in, short* __restrict__ hi, short* __restrict__ lo, int n4)
{
    const int i = blockIdx.x * 256 + threadIdx.x;
    if (i >= n4) return;
    f32x4 v = *(const f32x4*)(in + (size_t)i * 4);
    short h[4], l[4];
    #pragma unroll
    for (int j = 0; j < 4; ++j) {
        h[j] = f2bf(v[j]);
        l[j] = f2bf(v[j] - bf2f(h[j]));
    }
    typedef short short4_ __attribute__((ext_vector_type(4)));
    *(short4_*)(hi + (size_t)i * 4) = short4_{h[0], h[1], h[2], h[3]};
    *(short4_*)(lo + (size_t)i * 4) = short4_{l[0], l[1], l[2], l[3]};
}

// ---------------------------------------------------------------------------
// MFMA GEMM core: C[128x128] tile of A[M,K=1024] @ W[N,K=1024]^T using
// split-bf16: acc += Ah*Bh + Ah*Bl + Al*Bh.  Both operands K-contiguous.
// LDS tiles [128][32] bf16, XOR-swizzled 16B slots so ds_read_b128 is 2-way
// (free).  global_load_lds writes linearly; the SOURCE k-chunk is inverse-
// swizzled to compensate (rule: linear dest + inv-swz source + swz read).
// ---------------------------------------------------------------------------
__device__ __forceinline__ void gemm_core(
    const short* __restrict__ Ah_g, const short* __restrict__ Al_g,
    const short* __restrict__ Bh_g, const short* __restrict__ Bl_g,
    int row0, int col0, short* lds, f32x4 acc[4][4])
{
    const int t = threadIdx.x;
    const int lane = t & 63;
    const int w = t >> 6;
    const int wr = w >> 1, wc = w & 1;
    const int fr = lane & 15, kc = lane >> 4;

    for (int k0 = 0; k0 < DM; k0 += 32) {
        const short* a_h = Ah_g + (size_t)row0 * DM + k0;
        const short* a_l = Al_g + (size_t)row0 * DM + k0;
        const short* b_h = Bh_g + (size_t)col0 * DM + k0;
        const short* b_l = Bl_g + (size_t)col0 * DM + k0;
        #pragma unroll
        for (int p = 0; p < 2; ++p) {
            const int b = p * 4096 + t * 16;          // linear byte in 8 KB tile
            const int r = b >> 6;                     // row 0..127
            const int s = (b >> 4) & 3;               // 16B slot in row
            const int fsw = (r & 3) ^ ((r >> 2) & 3);
            const int c = ((s ^ fsw) << 3);           // inverse-swizzled k-elem
            const size_t go = (size_t)r * DM + c;
            GLOAD16(a_h + go, lds + 0 * 4096 + (b >> 1));
            GLOAD16(a_l + go, lds + 1 * 4096 + (b >> 1));
            GLOAD16(b_h + go, lds + 2 * 4096 + (b >> 1));
            GLOAD16(b_l + go, lds + 3 * 4096 + (b >> 1));
        }
        __syncthreads();

        short8 bhf[4], blf[4];
        #pragma unroll
        for (int n = 0; n < 4; ++n) {
            const int row = wc * 64 + n * 16 + fr;
            const int fsw = (row & 3) ^ ((row >> 2) & 3);
            const int off = row * 32 + ((kc ^ fsw) << 3);
            bhf[n] = *(const short8*)(lds + 2 * 4096 + off);
            blf[n] = *(const short8*)(lds + 3 * 4096 + off);
        }
        #pragma unroll
        for (int m = 0; m < 4; ++m) {
            const int row = wr * 64 + m * 16 + fr;
            const int fsw = (row & 3) ^ ((row >> 2) & 3);
            const int off = row * 32 + ((kc ^ fsw) << 3);
            short8 ahf = *(const short8*)(lds + 0 * 4096 + off);
            short8 alf = *(const short8*)(lds + 1 * 4096 + off);
            #pragma unroll
            for (int n = 0; n < 4; ++n) {
                acc[m][n] = __builtin_amdgcn_mfma_f32_16x16x32_bf16(ahf, bhf[n], acc[m][n], 0, 0, 0);
                acc[m][n] = __builtin_amdgcn_mfma_f32_16x16x32_bf16(ahf, blf[n], acc[m][n], 0, 0, 0);
                acc[m][n] = __builtin_amdgcn_mfma_f32_16x16x32_bf16(alf, bhf[n], acc[m][n], 0, 0, 0);
            }
        }
        __syncthreads();
    }
}

// QKV GEMM: z selects q/k/v.  Epilogue: +bias, sigmoid for q,k, scatter to
// [B,H,L,HD] f32.
__global__ __launch_bounds__(256) void gemm_qkv_kernel(
    const short* __restrict__ xh, const short* __restrict__ xl,
    const short* __restrict__ wh, const short* __restrict__ wl,   // packed 3x [DM][DM]
    const float* __restrict__ bq, const float* __restrict__ bk, const float* __restrict__ bv,
    float* __restrict__ qb, float* __restrict__ kb, float* __restrict__ vb)
{
    const int z = blockIdx.z;
    const float* __restrict__ bias = (z == 0) ? bq : (z == 1) ? bk : bv;
    float* __restrict__ outp       = (z == 0) ? qb : (z == 1) ? kb : vb;
    const short* Wh = wh + (size_t)z * DM * DM;
    const short* Wl = wl + (size_t)z * DM * DM;

    __shared__ short lds[4 * 4096];
    const int row0 = blockIdx.y * 128;
    const int col0 = blockIdx.x * 128;
    f32x4 acc[4][4];
    #pragma unroll
    for (int m = 0; m < 4; ++m)
        #pragma unroll
        for (int n = 0; n < 4; ++n) acc[m][n] = f32x4{0.f, 0.f, 0.f, 0.f};

    gemm_core(xh, xl, Wh, Wl, row0, col0, lds, acc);

    const int lane = threadIdx.x & 63;
    const int w = threadIdx.x >> 6;
    const int wr = w >> 1, wc = w & 1;
    const int fr = lane & 15, kc = lane >> 4;
    #pragma unroll
    for (int m = 0; m < 4; ++m) {
        const int gr0 = row0 + wr * 64 + m * 16 + kc * 4;
        #pragma unroll
        for (int n = 0; n < 4; ++n) {
            const int j = col0 + wc * 64 + n * 16 + fr;
            const float bj = bias[j];
            const int h = j >> 6, dd = j & 63;
            #pragma unroll
            for (int r2 = 0; r2 < 4; ++r2) {
                const int i = gr0 + r2;
                const int nn = i >> 11, l = i & (L_ - 1);
                float v = acc[m][n][r2] + bj;
                if (z < 2) v = sigmoidf_(v);
                outp[(((size_t)(nn * H_ + h)) * L_ + l) * HD_ + dd] = v;
            }
        }
    }
}

// Final GEMM: out = attn_hi/lo @ Wo^T + bo, plain [B*L, DM] f32 store.
__global__ __launch_bounds__(256) void gemm_out_kernel(
    const short* __restrict__ ah, const short* __restrict__ al,
    const short* __restrict__ wh, const short* __restrict__ wl,
    const float* __restrict__ bias, float* __restrict__ outp)
{
    __shared__ short lds[4 * 4096];
    const int row0 = blockIdx.y * 128;
    const int col0 = blockIdx.x * 128;
    f32x4 acc[4][4];
    #pragma unroll
    for (int m = 0; m < 4; ++m)
        #pragma unroll
        for (int n = 0; n < 4; ++n) acc[m][n] = f32x4{0.f, 0.f, 0.f, 0.f};

    gemm_core(ah, al, wh, wl, row0, col0, lds, acc);

    const int lane = threadIdx.x & 63;
    const int w = threadIdx.x >> 6;
    const int wr = w >> 1, wc = w & 1;
    const int fr = lane & 15, kc = lane >> 4;
    #pragma unroll
    for (int m = 0; m < 4; ++m) {
        const int gr0 = row0 + wr * 64 + m * 16 + kc * 4;
        #pragma unroll
        for (int n = 0; n < 4; ++n) {
            const int j = col0 + wc * 64 + n * 16 + fr;
            const float bj = bias[j];
            #pragma unroll
            for (int r2 = 0; r2 < 4; ++r2)
                outp[(size_t)(gr0 + r2) * DM + j] = acc[m][n][r2] + bj;
        }
    }
}

// ---------------------------------------------------------------------------
// colsum partials: qsum_p[nh][chunk][d] = sum over 128 l's
// ---------------------------------------------------------------------------
__global__ __launch_bounds__(256) void colsum_part_kernel(
    const float* __restrict__ q, const float* __restrict__ k,
    float* __restrict__ qsum_p, float* __restrict__ ksum_p)
{
    const int nh = blockIdx.x, ch = blockIdx.y;
    const float* qp = q + (size_t)nh * L_ * HD_;
    const float* kp = k + (size_t)nh * L_ * HD_;
    const int d = threadIdx.x & 63;
    const int c = threadIdx.x >> 6;
    float qs = 0.f, ks = 0.f;
    for (int l = ch * 128 + c; l < (ch + 1) * 128; l += 4) {
        qs += qp[(size_t)l * HD_ + d];
        ks += kp[(size_t)l * HD_ + d];
    }
    __shared__ float sq[4][64], sk[4][64];
    sq[c][d] = qs; sk[c][d] = ks;
    __syncthreads();
    if (c == 0) {
        qsum_p[(nh * 16 + ch) * 64 + d] = sq[0][d] + sq[1][d] + sq[2][d] + sq[3][d];
        ksum_p[(nh * 16 + ch) * 64 + d] = sk[0][d] + sk[1][d] + sk[2][d] + sk[3][d];
    }
}

// generic: reduce 16 chunk-partials for two arrays
__global__ __launch_bounds__(64) void reduce16_2_kernel(
    const float* __restrict__ ap, const float* __restrict__ bp,
    float* __restrict__ a, float* __restrict__ b)
{
    const int nh = blockIdx.x, d = threadIdx.x;
    float sa_ = 0.f, sb_ = 0.f;
    #pragma unroll
    for (int i = 0; i < 16; ++i) {
        sa_ += ap[(nh * 16 + i) * 64 + d];
        sb_ += bp[(nh * 16 + i) * 64 + d];
    }
    a[nh * 64 + d] = sa_;
    b[nh * 64 + d] = sb_;
}

// ---------------------------------------------------------------------------
// stage1: per l compute si (stored), so (used inline); partial qsi/kso.
// ---------------------------------------------------------------------------
__global__ __launch_bounds__(256) void stage1_part_kernel(
    const float* __restrict__ q, const float* __restrict__ k,
    const float* __restrict__ qsum, const float* __restrict__ ksum,
    float* __restrict__ si, float* __restrict__ qsi_p, float* __restrict__ kso_p)
{
    const int nh = blockIdx.x, ch = blockIdx.y;
    const float* qp = q + (size_t)nh * L_ * HD_;
    const float* kp = k + (size_t)nh * L_ * HD_;
    const int lane = threadIdx.x & 63;
    const int w = threadIdx.x >> 6;
    const float ksv = ksum[nh * 64 + lane] + EPS_;
    const float qsv = qsum[nh * 64 + lane] + EPS_;
    float qsi_acc = 0.f, kso_acc = 0.f;
    for (int l = ch * 128 + w; l < (ch + 1) * 128; l += 4) {
        const float qv = qp[(size_t)l * HD_ + lane];
        const float kv = kp[(size_t)l * HD_ + lane];
        float a = (qv + EPS_) * ksv;
        float b = (kv + EPS_) * qsv;
        #pragma unroll
        for (int off = 32; off >= 1; off >>= 1) {
            a += __shfl_xor(a, off, 64);
            b += __shfl_xor(b, off, 64);
        }
        const float siv = 1.f / a;
        const float sov = 1.f / b;
        if (lane == 0) si[nh * L_ + l] = siv;
        qsi_acc += qv * siv;
        kso_acc += kv * sov;
    }
    __shared__ float s1[4][64], s2[4][64];
    s1[w][lane] = qsi_acc; s2[w][lane] = kso_acc;
    __syncthreads();
    if (w == 0) {
        qsi_p[(nh * 16 + ch) * 64 + lane] = s1[0][lane] + s1[1][lane] + s1[2][lane] + s1[3][lane];
        kso_p[(nh * 16 + ch) * 64 + lane] = s2[0][lane] + s2[1][lane] + s2[2][lane] + s2[3][lane];
    }
}

// ---------------------------------------------------------------------------
// stage2: sa = sigmoid(conserved_sink); sc_raw = exp(clip(conserved_source));
// psum partials for softmax denominator.
// ---------------------------------------------------------------------------
__global__ __launch_bounds__(256) void stage2_part_kernel(
    const float* __restrict__ q, const float* __restrict__ k,
    const float* __restrict__ qsi, const float* __restrict__ kso,
    float* __restrict__ sa, float* __restrict__ sc, float* __restrict__ psum_p)
{
    const int nh = blockIdx.x, ch = blockIdx.y;
    const float* qp = q + (size_t)nh * L_ * HD_;
    const float* kp = k + (size_t)nh * L_ * HD_;
    const int lane = threadIdx.x & 63;
    const int w = threadIdx.x >> 6;
    const float ksov = kso[nh * 64 + lane] + EPS_;
    const float qsiv = qsi[nh * 64 + lane] + EPS_;
    float psum = 0.f;
    for (int l = ch * 128 + w; l < (ch + 1) * 128; l += 4) {
        float a = (qp[(size_t)l * HD_ + lane] + EPS_) * ksov;
        float b = (kp[(size_t)l * HD_ + lane] + EPS_) * qsiv;
        #pragma unroll
        for (int off = 32; off >= 1; off >>= 1) {
            a += __shfl_xor(a, off, 64);
            b += __shfl_xor(b, off, 64);
        }
        b = fminf(1.f, fmaxf(-1.f, b));
        const float p = expf(b);
        if (lane == 0) {
            sa[nh * L_ + l] = sigmoidf_(a);
            sc[nh * L_ + l] = p;
        }
        psum += p;    // same on all lanes of wave
    }
    __shared__ float sp[4];
    if (lane == 0) sp[w] = psum;
    __syncthreads();
    if (threadIdx.x == 0) psum_p[nh * 16 + ch] = sp[0] + sp[1] + sp[2] + sp[3];
}

// ---------------------------------------------------------------------------
// kv partial over 256-l chunk: kvp[nh][ch][d][m] = sum k[l][d]*v[l][m]*sc[l]*scale
// ---------------------------------------------------------------------------
__global__ __launch_bounds__(256) void kv_part_kernel(
    const float* __restrict__ k, const float* __restrict__ v,
    const float* __restrict__ sc, const float* __restrict__ psum_p,
    float* __restrict__ kvp)
{
    const int nh = blockIdx.x, ch = blockIdx.y;
    const float* kp = k + (size_t)nh * L_ * HD_;
    const float* vp = v + (size_t)nh * L_ * HD_;
    const float* scp = sc + (size_t)nh * L_;
    float tot = 0.f;
    #pragma unroll
    for (int i = 0; i < 16; ++i) tot += psum_p[nh * 16 + i];
    const float scale = (float)L_ / tot;

    const int m  = threadIdx.x & 63;
    const int dg = threadIdx.x >> 6;
    float acc[16] = {0.f};
    __shared__ float ks[32][64], vs[32][64];
    for (int l0 = ch * 256; l0 < (ch + 1) * 256; l0 += 32) {
        for (int i = threadIdx.x; i < 32 * 64; i += 256) {
            const int ll = i >> 6, dd = i & 63;
            ks[ll][dd] = kp[(size_t)(l0 + ll) * HD_ + dd];
            vs[ll][dd] = vp[(size_t)(l0 + ll) * HD_ + dd] * (scp[l0 + ll] * scale);
        }
        __syncthreads();
        #pragma unroll 8
        for (int ll = 0; ll < 32; ++ll) {
            const float vv = vs[ll][m];
            #pragma unroll
            for (int dd = 0; dd < 16; ++dd) acc[dd] += ks[ll][dg * 16 + dd] * vv;
        }
        __syncthreads();
    }
    #pragma unroll
    for (int dd = 0; dd < 16; ++dd)
        kvp[((size_t)(nh * 8 + ch) * 64 + (dg * 16 + dd)) * 64 + m] = acc[dd];
}

__global__ __launch_bounds__(256) void kv_reduce_kernel(
    const float* __restrict__ kvp, float* __restrict__ kvb)
{
    const int nh = blockIdx.x;
    for (int e = threadIdx.x; e < 4096; e += 256) {
        float s = 0.f;
        #pragma unroll
        for (int c = 0; c < 8; ++c) s += kvp[(size_t)(nh * 8 + c) * 4096 + e];
        kvb[(size_t)nh * 4096 + e] = s;
    }
}

// ---------------------------------------------------------------------------
// out: attn[n][l][h*64+m] = sa*si*(q[l,:]·kv[:,m]) -> bf16 hi/lo split store
// ---------------------------------------------------------------------------
__global__ __launch_bounds__(256) void out_kernel(
    const float* __restrict__ q, const float* __restrict__ kvb,
    const float* __restrict__ si, const float* __restrict__ sa,
    short* __restrict__ attn_h, short* __restrict__ attn_l)
{
    const int nh = blockIdx.x;
    const int n = nh >> 4;
    const int h = nh & 15;
    const int l0 = blockIdx.y * 64;
    __shared__ float kvs[64][64];
    __shared__ float qs[64][64];
    for (int i = threadIdx.x; i < 4096; i += 256)
        kvs[i >> 6][i & 63] = kvb[(size_t)nh * 4096 + i];
    for (int i = threadIdx.x; i < 4096; i += 256) {
        const int ll = i >> 6, dd = i & 63;
        qs[ll][dd] = q[((size_t)nh * L_ + (l0 + ll)) * HD_ + dd];
    }
    __syncthreads();
    const int m = threadIdx.x & 63;
    const int lg = threadIdx.x >> 6;
    for (int ll = lg; ll < 64; ll += 4) {
        const int l = l0 + ll;
        float acc = 0.f;
        #pragma unroll
        for (int d = 0; d < 64; ++d) acc += qs[ll][d] * kvs[d][m];
        const float val = acc * si[nh * L_ + l] * sa[nh * L_ + l];
        const size_t idx = ((size_t)n * L_ + l) * DM + h * 64 + m;
        const short hb = f2bf(val);
        attn_h[idx] = hb;
        attn_l[idx] = f2bf(val - bf2f(hb));
    }
}

extern "C" void kernel_launch(void* const* d_in, const int* in_sizes, int n_in,
                              void* d_out, int out_size, void* d_ws, size_t ws_size,
                              hipStream_t stream)
{
    const float* x  = (const float*)d_in[0];
    const float* Wq = (const float*)d_in[1];
    const float* bq = (const float*)d_in[2];
    const float* Wk = (const float*)d_in[3];
    const float* bk = (const float*)d_in[4];
    const float* Wv = (const float*)d_in[5];
    const float* bv = (const float*)d_in[6];
    const float* Wo = (const float*)d_in[7];
    const float* bo = (const float*)d_in[8];
    float* out = (float*)d_out;

    float* ws = (float*)d_ws;
    size_t off = 0;
    const size_t big = (size_t)B_ * L_ * DM;   // 8,388,608 elems
    float* qbuf = ws + off; off += big;
    float* kbuf = ws + off; off += big;
    float* vbuf = ws + off; off += big;
    // union region: x hi/lo during projections, attn hi/lo afterwards (each big shorts)
    short* xh = (short*)(ws + off);            // big shorts
    short* xl = xh + big;                      // big shorts -> region = big floats total
    short* attn_h = xh;
    short* attn_l = xl;
    off += big;
    // W splits: [3][DM][DM] for qkv + [DM][DM] for o, hi & lo
    short* wh3 = (short*)(ws + off); off += (size_t)3 * DM * DM / 2;
    short* wl3 = (short*)(ws + off); off += (size_t)3 * DM * DM / 2;
    short* woh = (short*)(ws + off); off += (size_t)DM * DM / 2;
    short* wol = (short*)(ws + off); off += (size_t)DM * DM / 2;
    float* kvp    = ws + off; off += (size_t)NH_ * 8 * 64 * 64;
    float* kvb    = ws + off; off += (size_t)NH_ * 64 * 64;
    float* qsum_p = ws + off; off += NH_ * 16 * 64;
    float* ksum_p = ws + off; off += NH_ * 16 * 64;
    float* qsi_p  = ws + off; off += NH_ * 16 * 64;
    float* kso_p  = ws + off; off += NH_ * 16 * 64;
    float* psum_p = ws + off; off += NH_ * 16;
    float* qsum   = ws + off; off += NH_ * 64;
    float* ksum   = ws + off; off += NH_ * 64;
    float* qsi    = ws + off; off += NH_ * 64;
    float* kso    = ws + off; off += NH_ * 64;
    float* si     = ws + off; off += NH_ * L_;
    float* sa     = ws + off; off += NH_ * L_;
    float* sc     = ws + off; off += NH_ * L_;

    // 1. split inputs to bf16 hi/lo
    split_kernel<<<big / 4 / 256, 256, 0, stream>>>(x, xh, xl, (int)(big / 4));
    const int wblk = DM * DM / 4 / 256;   // 1024
    split_kernel<<<wblk, 256, 0, stream>>>(Wq, wh3,               wl3,               DM * DM / 4);
    split_kernel<<<wblk, 256, 0, stream>>>(Wk, wh3 + DM * DM,     wl3 + DM * DM,     DM * DM / 4);
    split_kernel<<<wblk, 256, 0, stream>>>(Wv, wh3 + 2 * DM * DM, wl3 + 2 * DM * DM, DM * DM / 4);
    split_kernel<<<wblk, 256, 0, stream>>>(Wo, woh,               wol,               DM * DM / 4);

    // 2. QKV projection GEMMs (MFMA)
    dim3 gqkv(DM / 128, (B_ * L_) / 128, 3);
    gemm_qkv_kernel<<<gqkv, 256, 0, stream>>>(xh, xl, wh3, wl3, bq, bk, bv, qbuf, kbuf, vbuf);

    // 3. flow-conservation normalizations
    dim3 g16(NH_, 16);
    colsum_part_kernel<<<g16, 256, 0, stream>>>(qbuf, kbuf, qsum_p, ksum_p);
    reduce16_2_kernel<<<NH_, 64, 0, stream>>>(qsum_p, ksum_p, qsum, ksum);
    stage1_part_kernel<<<g16, 256, 0, stream>>>(qbuf, kbuf, qsum, ksum, si, qsi_p, kso_p);
    reduce16_2_kernel<<<NH_, 64, 0, stream>>>(qsi_p, kso_p, qsi, kso);
    stage2_part_kernel<<<g16, 256, 0, stream>>>(qbuf, kbuf, qsi, kso, sa, sc, psum_p);

    // 4. linear-attention kv + out
    kv_part_kernel<<<dim3(NH_, 8), 256, 0, stream>>>(kbuf, vbuf, sc, psum_p, kvp);
    kv_reduce_kernel<<<NH_, 256, 0, stream>>>(kvp, kvb);
    out_kernel<<<dim3(NH_, L_ / 64), 256, 0, stream>>>(qbuf, kvb, si, sa, attn_h, attn_l);

    // 5. output projection GEMM (MFMA)
    dim3 gout(DM / 128, (B_ * L_) / 128);
    gemm_out_kernel<<<gout, 256, 0, stream>>>(attn_h, attn_l, woh, wol, bo, out);
}